// Round 6
// baseline (626.487 us; speedup 1.0000x reference)
//
#include <hip/hip_runtime.h>
#include <hip/hip_bf16.h>
#include <stdint.h>

#define E_ 8
#define B_ 4096
#define D_ 2048
#define T_ 2048
#define H_ 2048
#define KDIM 2048
#define NDIM 2048

typedef __attribute__((ext_vector_type(4))) float f32x4;
typedef __attribute__((ext_vector_type(4))) unsigned short u16x4;
typedef __attribute__((ext_vector_type(8))) unsigned short u16x8;
typedef __attribute__((ext_vector_type(8))) __bf16 bf16x8;

__device__ __forceinline__ unsigned short f2bf(float f) {
    __hip_bfloat16 h = __float2bfloat16(f);
    return __builtin_bit_cast(unsigned short, h);
}

__device__ __forceinline__ void gload_lds16(const void* g, void* lds) {
    __builtin_amdgcn_global_load_lds(
        (const __attribute__((address_space(1))) void*)g,
        (__attribute__((address_space(3))) void*)lds, 16, 0, 0);
}

// ---------------------------------------------------------------------------
// Gating: f32 logits (exact ranking), softmax, top-2, per-expert slot lists.
// Packs the 2 selected xs rows (held in registers) to bf16 A1[slot][D].
// ---------------------------------------------------------------------------
__global__ __launch_bounds__(256) void moe_gating(
    const float* __restrict__ xs, const float* __restrict__ Wg,
    const float* __restrict__ bg, float* __restrict__ out_topk,
    float* __restrict__ prob_slot, int* __restrict__ counts,
    int* __restrict__ slot_of, unsigned short* __restrict__ A1)
{
    const int b = blockIdx.x;
    const int t = threadIdx.x;
    const int wave = t >> 6, lane = t & 63;
    __shared__ float red[E_][4];
    __shared__ int sh_i0, sh_i1;

    const f32x4 wg0 = ((const f32x4*)Wg)[t];
    const f32x4 wg1 = ((const f32x4*)Wg)[t + 256];

    f32x4 xa[E_], xb[E_];
    #pragma unroll
    for (int e = 0; e < E_; ++e) {
        const f32x4* xr = (const f32x4*)(xs + ((size_t)e * B_ + b) * D_);
        xa[e] = __builtin_nontemporal_load(&xr[t]);
        xb[e] = __builtin_nontemporal_load(&xr[t + 256]);
        float p = xa[e].x*wg0.x + xa[e].y*wg0.y + xa[e].z*wg0.z + xa[e].w*wg0.w
                + xb[e].x*wg1.x + xb[e].y*wg1.y + xb[e].z*wg1.z + xb[e].w*wg1.w;
        #pragma unroll
        for (int off = 32; off >= 1; off >>= 1) p += __shfl_xor(p, off);
        if (lane == 0) red[e][wave] = p;
    }
    __syncthreads();
    if (t == 0) {
        float pr[E_];
        float mx = -3.0e38f;
        #pragma unroll
        for (int e = 0; e < E_; ++e) {
            pr[e] = red[e][0] + red[e][1] + red[e][2] + red[e][3] + bg[0];
            mx = fmaxf(mx, pr[e]);
        }
        float s = 0.f;
        #pragma unroll
        for (int e = 0; e < E_; ++e) { pr[e] = expf(pr[e] - mx); s += pr[e]; }
        float inv = 1.0f / s;
        #pragma unroll
        for (int e = 0; e < E_; ++e) pr[e] *= inv;
        int i0 = 0;
        #pragma unroll
        for (int e = 1; e < E_; ++e) if (pr[e] > pr[i0]) i0 = e;
        int i1 = (i0 == 0) ? 1 : 0;
        #pragma unroll
        for (int e = 0; e < E_; ++e) { if (e != i0 && pr[e] > pr[i1]) i1 = e; }
        float p0 = pr[i0], p1 = pr[i1];
        out_topk[2*b]    = p0;
        out_topk[2*b+1]  = p1;
        prob_slot[2*b]   = p0;
        prob_slot[2*b+1] = p1;
        int pos0 = atomicAdd(&counts[i0], 1);
        slot_of[i0 * B_ + pos0] = 2*b;
        int pos1 = atomicAdd(&counts[i1], 1);
        slot_of[i1 * B_ + pos1] = 2*b + 1;
        sh_i0 = i0; sh_i1 = i1;
    }
    __syncthreads();
    const int i0 = sh_i0, i1 = sh_i1;
    f32x4 s0a = xa[0], s0b = xb[0], s1a = xa[0], s1b = xb[0];
    #pragma unroll
    for (int e = 0; e < E_; ++e) {
        if (i0 == e) { s0a = xa[e]; s0b = xb[e]; }
        if (i1 == e) { s1a = xa[e]; s1b = xb[e]; }
    }
    u16x4 w;
    w[0]=f2bf(s0a.x); w[1]=f2bf(s0a.y); w[2]=f2bf(s0a.z); w[3]=f2bf(s0a.w);
    ((u16x4*)(A1 + (size_t)(2*b) * D_))[t] = w;
    w[0]=f2bf(s0b.x); w[1]=f2bf(s0b.y); w[2]=f2bf(s0b.z); w[3]=f2bf(s0b.w);
    ((u16x4*)(A1 + (size_t)(2*b) * D_ + 1024))[t] = w;
    w[0]=f2bf(s1a.x); w[1]=f2bf(s1a.y); w[2]=f2bf(s1a.z); w[3]=f2bf(s1a.w);
    ((u16x4*)(A1 + (size_t)(2*b+1) * D_))[t] = w;
    w[0]=f2bf(s1b.x); w[1]=f2bf(s1b.y); w[2]=f2bf(s1b.z); w[3]=f2bf(s1b.w);
    ((u16x4*)(A1 + (size_t)(2*b+1) * D_ + 1024))[t] = w;
}

// ---------------------------------------------------------------------------
// Build compact (expert, m-tile) work list, M-tile = 128. Max entries = 72.
// ---------------------------------------------------------------------------
__global__ void build_tiles(const int* __restrict__ counts, int* __restrict__ tiles)
{
    if (threadIdx.x == 0 && blockIdx.x == 0) {
        int n = 0;
        for (int e = 0; e < E_; ++e) {
            int te = (counts[e] + 127) >> 7;
            for (int m = 0; m < te; ++m) tiles[1 + n++] = (e << 16) | m;
        }
        tiles[0] = n;
    }
}

// ---------------------------------------------------------------------------
// Weight transpose-convert: W[e][K][N] f32 -> Wt[e][N][K] bf16, 64x64 tiles.
// ---------------------------------------------------------------------------
__global__ __launch_bounds__(256) void wtrans(
    const float* __restrict__ W, unsigned short* __restrict__ Wt)
{
    const int e  = blockIdx.z;
    const int kb = blockIdx.x * 64;
    const int nb = blockIdx.y * 64;
    const int t  = threadIdx.x;
    __shared__ float tile[64][68];

    const float* src = W + ((size_t)e * KDIM + kb) * NDIM + nb;
    {
        const int kr = t >> 2, nc = (t & 3) * 16;
        #pragma unroll
        for (int j = 0; j < 4; ++j) {
            f32x4 v = __builtin_nontemporal_load(
                (const f32x4*)(src + (size_t)kr * NDIM + nc + j * 4));
            *(f32x4*)&tile[kr][nc + j * 4] = v;
        }
    }
    __syncthreads();
    {
        const int nn = t >> 2, kc = (t & 3) * 16;
        unsigned short wbuf[16];
        #pragma unroll
        for (int j = 0; j < 16; ++j) wbuf[j] = f2bf(tile[kc + j][nn]);
        unsigned short* dst = Wt + ((size_t)e * NDIM + nb + nn) * KDIM + kb + kc;
        *(u16x8*)dst       = *(const u16x8*)&wbuf[0];
        *((u16x8*)dst + 1) = *(const u16x8*)&wbuf[8];
    }
}

// ---------------------------------------------------------------------------
// 128x128 expert GEMM, BK=32, 4 waves (2x2), 4 LDS buffer pairs (64 KB ->
// 2 blocks/CU), DEPTH-3 prefetch with counted vmcnt(8) (never 0 in-loop),
// single barrier per K-tile. LDS unit swizzle u = kblk ^ ((row>>1)&3):
// conflict-free (8-beat) ds_read_b128, DMA-source pre-swizzled (rule #21).
// XCD-grouped item mapping keeps an m-tile's 16 n-panels on one XCD.
// ---------------------------------------------------------------------------
#define BAR  __builtin_amdgcn_s_barrier()

template<int LAYER>
__global__ __launch_bounds__(256, 2) void moe_gemm(
    const unsigned short* __restrict__ Abuf,
    const unsigned short* __restrict__ Wt,
    const float* __restrict__ bias,
    const int* __restrict__ counts,
    const int* __restrict__ tiles,
    const int* __restrict__ slot_of,
    const float* __restrict__ prob_slot,
    unsigned short* __restrict__ hidden_out,
    float* __restrict__ out)
{
    // item decode: bid = ((mtg*16)+np)*8 + xcd; mt = mtg*8 + xcd
    const int nMt = tiles[0];
    const int bid = blockIdx.x;
    const int xcd = bid & 7;
    const int kq  = bid >> 3;
    const int np  = kq & 15;
    const int mtg = kq >> 4;
    const int mt  = mtg * 8 + xcd;
    if (mt >= nMt) return;
    const int info = tiles[1 + mt];
    const int e   = info >> 16;
    const int m0  = (info & 0xffff) * 128;
    const int n0  = np * 128;
    const int n_e = counts[e];

    const int t = threadIdx.x;
    const int lane = t & 63;
    const int w = t >> 6;
    const int wm = (w >> 1) * 64;
    const int wn = (w & 1) * 64;
    const int lg = lane >> 4;

    __shared__ u16x8 As[4 * 512];   // 4 bufs x 128 rows x 4 units (32 KB)
    __shared__ u16x8 Bs[4 * 512];
    __shared__ int   slots_s[128];
    __shared__ float probs_s[128];

    if (t < 128) {
        int gm = m0 + t;
        int s = -1; float p = 0.f;
        if (gm < n_e) { s = slot_of[e * B_ + gm]; p = prob_slot[s]; }
        slots_s[t] = s; probs_s[t] = p;
    }
    __syncthreads();

    // staging: wave w covers rows [w*32, w*32+32) via 2 gloads (16 rows each).
    // lane l -> row base+(l>>2), stored unit (l&3); source kblk pre-swizzled:
    // k16 = (l&3) ^ ((l>>3)&3)   [= stored_unit ^ ((row>>1)&3), involution]
    const int ksw = (((lane & 3) ^ ((lane >> 3) & 3)) << 3);   // bf16 elems
    const unsigned short* aptr[2];
    const unsigned short* bptr[2];
    #pragma unroll
    for (int j = 0; j < 2; ++j) {
        const int r = w * 32 + j * 16 + (lane >> 2);
        int s = slots_s[r]; if (s < 0) s = 0;
        aptr[j] = Abuf + (size_t)s * KDIM + ksw;
        bptr[j] = Wt + ((size_t)e * NDIM + n0 + r) * KDIM + ksw;
    }

#define STG(BUF, KT) do{ \
    _Pragma("unroll") \
    for (int j = 0; j < 2; ++j) { \
        gload_lds16(aptr[j] + (KT)*32, &As[(BUF)*512 + w*128 + j*64]); \
        gload_lds16(bptr[j] + (KT)*32, &Bs[(BUF)*512 + w*128 + j*64]); } }while(0)

    f32x4 acc[4][4];
    #pragma unroll
    for (int i = 0; i < 4; ++i)
        #pragma unroll
        for (int j = 0; j < 4; ++j) {
            f32x4 z = {0.f, 0.f, 0.f, 0.f};
            acc[i][j] = z;
        }

    // prologue: 3 tiles in flight (12 loads/wave)
    STG(0, 0); STG(1, 1); STG(2, 2);

    const int usw = (lane >> 1) & 3;   // ds_read unit swizzle = (row>>1)&3
    for (int kt = 0; kt < 64; ++kt) {
        asm volatile("s_waitcnt vmcnt(8)" ::: "memory");   // tile kt landed
        BAR;
        int tn = kt + 3; if (tn > 63) tn = 63;             // clamped dummy tail
        STG((kt + 3) & 3, tn);

        const int base = (kt & 3) * 512;
        bf16x8 af[4], bq[4];
        #pragma unroll
        for (int mi = 0; mi < 4; ++mi) {
            const int row = wm + mi * 16 + (lane & 15);
            af[mi] = __builtin_bit_cast(bf16x8, As[base + row * 4 + (lg ^ usw)]);
        }
        #pragma unroll
        for (int ni = 0; ni < 4; ++ni) {
            const int row = wn + ni * 16 + (lane & 15);
            bq[ni] = __builtin_bit_cast(bf16x8, Bs[base + row * 4 + (lg ^ usw)]);
        }
        #pragma unroll
        for (int mi = 0; mi < 4; ++mi)
            #pragma unroll
            for (int ni = 0; ni < 4; ++ni)
                acc[mi][ni] = __builtin_amdgcn_mfma_f32_16x16x32_bf16(
                    af[mi], bq[ni], acc[mi][ni], 0, 0, 0);
    }
    asm volatile("s_waitcnt vmcnt(0)" ::: "memory");   // drain dummies

    // epilogue — C/D layout: col = lane&15, row = (lane>>4)*4 + reg
    #pragma unroll
    for (int mi = 0; mi < 4; ++mi) {
        #pragma unroll
        for (int rr = 0; rr < 4; ++rr) {
            const int rloc = wm + mi * 16 + ((lane >> 4) << 2) + rr;
            const int s = slots_s[rloc];
            if (s < 0) continue;
            #pragma unroll
            for (int ni = 0; ni < 4; ++ni) {
                const int col = n0 + wn + ni * 16 + (lane & 15);
                float v = acc[mi][ni][rr];
                if (LAYER == 1) {
                    v += bias[e * NDIM + col];
                    v = fmaxf(v, 0.f);
                    hidden_out[(size_t)s * H_ + col] = f2bf(v);
                } else {
                    v = (v + bias[e * NDIM + col]) * probs_s[rloc];
                    atomicAdd(&out[(size_t)(s >> 1) * T_ + col], v);
                }
            }
        }
    }
#undef STG
}

// ---------------------------------------------------------------------------
// ws layout: counts@0 (256B) | tiles@256 (512B) | slot_of | prob_slot |
//            A1[2B][D] bf16 | hidden[2B][H] bf16 | Wt bf16
// ---------------------------------------------------------------------------
extern "C" void kernel_launch(void* const* d_in, const int* in_sizes, int n_in,
                              void* d_out, int out_size, void* d_ws, size_t ws_size,
                              hipStream_t stream)
{
    const float* xs = (const float*)d_in[0];
    const float* Wg = (const float*)d_in[1];
    const float* bg = (const float*)d_in[2];
    const float* W1 = (const float*)d_in[3];
    const float* b1 = (const float*)d_in[4];
    const float* W2 = (const float*)d_in[5];
    const float* b2 = (const float*)d_in[6];

    float* out      = (float*)d_out;
    float* out_topk = out + (size_t)B_ * T_;

    char* ws = (char*)d_ws;
    int*   counts    = (int*)ws;
    int*   tiles     = (int*)(ws + 256);
    int*   slot_of   = (int*)(ws + 768);
    float* prob_slot = (float*)(ws + 768 + E_ * B_ * 4);
    size_t off = 768 + (size_t)E_ * B_ * 4 + 2 * B_ * 4;
    off = (off + 255) & ~(size_t)255;
    unsigned short* A1     = (unsigned short*)(ws + off); off += (size_t)2 * B_ * D_ * 2;
    unsigned short* hidden = (unsigned short*)(ws + off); off += (size_t)2 * B_ * H_ * 2;
    unsigned short* Wtb    = (unsigned short*)(ws + off);

    hipMemsetAsync(counts, 0, 256, stream);
    hipMemsetAsync(out, 0, (size_t)B_ * T_ * sizeof(float), stream);

    dim3 tgrid(32, 32, E_), blk(256);
    dim3 ggrid(9 * 16 * 8);   // 1152 blocks (worst case 72 m-tiles x 16 panels)

    moe_gating<<<dim3(B_), dim3(256), 0, stream>>>(
        xs, Wg, bg, out_topk, prob_slot, counts, slot_of, A1);
    build_tiles<<<dim3(1), dim3(64), 0, stream>>>(counts, tiles);

    wtrans<<<tgrid, blk, 0, stream>>>(W1, Wtb);
    moe_gemm<1><<<ggrid, blk, 0, stream>>>(
        A1, Wtb, b1, counts, tiles, slot_of, prob_slot, hidden, nullptr);

    wtrans<<<tgrid, blk, 0, stream>>>(W2, Wtb);
    moe_gemm<2><<<ggrid, blk, 0, stream>>>(
        hidden, Wtb, b2, counts, tiles, slot_of, prob_slot, nullptr, out);
}

// Round 7
// 527.941 us; speedup vs baseline: 1.1867x; 1.1867x over previous
//
#include <hip/hip_runtime.h>
#include <hip/hip_bf16.h>
#include <stdint.h>

#define E_ 8
#define B_ 4096
#define D_ 2048
#define T_ 2048
#define H_ 2048
#define KDIM 2048
#define NDIM 2048

typedef __attribute__((ext_vector_type(4))) float f32x4;
typedef __attribute__((ext_vector_type(4))) unsigned short u16x4;
typedef __attribute__((ext_vector_type(8))) unsigned short u16x8;
typedef __attribute__((ext_vector_type(8))) __bf16 bf16x8;

__device__ __forceinline__ unsigned short f2bf(float f) {
    __hip_bfloat16 h = __float2bfloat16(f);
    return __builtin_bit_cast(unsigned short, h);
}

__device__ __forceinline__ void gload_lds16(const void* g, void* lds) {
    __builtin_amdgcn_global_load_lds(
        (const __attribute__((address_space(1))) void*)g,
        (__attribute__((address_space(3))) void*)lds, 16, 0, 0);
}

// ---------------------------------------------------------------------------
// Gating: f32 logits (exact ranking), softmax, top-2, per-expert slot lists.
// Packs the 2 selected xs rows (held in registers) to bf16 A1[slot][D].
// ---------------------------------------------------------------------------
__global__ __launch_bounds__(256) void moe_gating(
    const float* __restrict__ xs, const float* __restrict__ Wg,
    const float* __restrict__ bg, float* __restrict__ out_topk,
    float* __restrict__ prob_slot, int* __restrict__ counts,
    int* __restrict__ slot_of, unsigned short* __restrict__ A1)
{
    const int b = blockIdx.x;
    const int t = threadIdx.x;
    const int wave = t >> 6, lane = t & 63;
    __shared__ float red[E_][4];
    __shared__ int sh_i0, sh_i1;

    const f32x4 wg0 = ((const f32x4*)Wg)[t];
    const f32x4 wg1 = ((const f32x4*)Wg)[t + 256];

    f32x4 xa[E_], xb[E_];
    #pragma unroll
    for (int e = 0; e < E_; ++e) {
        const f32x4* xr = (const f32x4*)(xs + ((size_t)e * B_ + b) * D_);
        xa[e] = __builtin_nontemporal_load(&xr[t]);
        xb[e] = __builtin_nontemporal_load(&xr[t + 256]);
        float p = xa[e].x*wg0.x + xa[e].y*wg0.y + xa[e].z*wg0.z + xa[e].w*wg0.w
                + xb[e].x*wg1.x + xb[e].y*wg1.y + xb[e].z*wg1.z + xb[e].w*wg1.w;
        #pragma unroll
        for (int off = 32; off >= 1; off >>= 1) p += __shfl_xor(p, off);
        if (lane == 0) red[e][wave] = p;
    }
    __syncthreads();
    if (t == 0) {
        float pr[E_];
        float mx = -3.0e38f;
        #pragma unroll
        for (int e = 0; e < E_; ++e) {
            pr[e] = red[e][0] + red[e][1] + red[e][2] + red[e][3] + bg[0];
            mx = fmaxf(mx, pr[e]);
        }
        float s = 0.f;
        #pragma unroll
        for (int e = 0; e < E_; ++e) { pr[e] = expf(pr[e] - mx); s += pr[e]; }
        float inv = 1.0f / s;
        #pragma unroll
        for (int e = 0; e < E_; ++e) pr[e] *= inv;
        int i0 = 0;
        #pragma unroll
        for (int e = 1; e < E_; ++e) if (pr[e] > pr[i0]) i0 = e;
        int i1 = (i0 == 0) ? 1 : 0;
        #pragma unroll
        for (int e = 0; e < E_; ++e) { if (e != i0 && pr[e] > pr[i1]) i1 = e; }
        float p0 = pr[i0], p1 = pr[i1];
        out_topk[2*b]    = p0;
        out_topk[2*b+1]  = p1;
        prob_slot[2*b]   = p0;
        prob_slot[2*b+1] = p1;
        int pos0 = atomicAdd(&counts[i0], 1);
        slot_of[i0 * B_ + pos0] = 2*b;
        int pos1 = atomicAdd(&counts[i1], 1);
        slot_of[i1 * B_ + pos1] = 2*b + 1;
        sh_i0 = i0; sh_i1 = i1;
    }
    __syncthreads();
    const int i0 = sh_i0, i1 = sh_i1;
    f32x4 s0a = xa[0], s0b = xb[0], s1a = xa[0], s1b = xb[0];
    #pragma unroll
    for (int e = 0; e < E_; ++e) {
        if (i0 == e) { s0a = xa[e]; s0b = xb[e]; }
        if (i1 == e) { s1a = xa[e]; s1b = xb[e]; }
    }
    u16x4 w;
    w[0]=f2bf(s0a.x); w[1]=f2bf(s0a.y); w[2]=f2bf(s0a.z); w[3]=f2bf(s0a.w);
    ((u16x4*)(A1 + (size_t)(2*b) * D_))[t] = w;
    w[0]=f2bf(s0b.x); w[1]=f2bf(s0b.y); w[2]=f2bf(s0b.z); w[3]=f2bf(s0b.w);
    ((u16x4*)(A1 + (size_t)(2*b) * D_ + 1024))[t] = w;
    w[0]=f2bf(s1a.x); w[1]=f2bf(s1a.y); w[2]=f2bf(s1a.z); w[3]=f2bf(s1a.w);
    ((u16x4*)(A1 + (size_t)(2*b+1) * D_))[t] = w;
    w[0]=f2bf(s1b.x); w[1]=f2bf(s1b.y); w[2]=f2bf(s1b.z); w[3]=f2bf(s1b.w);
    ((u16x4*)(A1 + (size_t)(2*b+1) * D_ + 1024))[t] = w;
}

// ---------------------------------------------------------------------------
// Build compact (expert, m-tile) work list, M-tile = 256. Max entries = 39.
// ---------------------------------------------------------------------------
__global__ void build_tiles(const int* __restrict__ counts, int* __restrict__ tiles)
{
    if (threadIdx.x == 0 && blockIdx.x == 0) {
        int n = 0;
        for (int e = 0; e < E_; ++e) {
            int te = (counts[e] + 255) >> 8;
            for (int m = 0; m < te; ++m) tiles[1 + n++] = (e << 16) | m;
        }
        tiles[0] = n;
    }
}

// ---------------------------------------------------------------------------
// Weight transpose-convert: W[e][K][N] f32 -> Wt[e][N][K] bf16, 64x64 tiles.
// ---------------------------------------------------------------------------
__global__ __launch_bounds__(256) void wtrans(
    const float* __restrict__ W, unsigned short* __restrict__ Wt)
{
    const int e  = blockIdx.z;
    const int kb = blockIdx.x * 64;
    const int nb = blockIdx.y * 64;
    const int t  = threadIdx.x;
    __shared__ float tile[64][68];

    const float* src = W + ((size_t)e * KDIM + kb) * NDIM + nb;
    {
        const int kr = t >> 2, nc = (t & 3) * 16;
        #pragma unroll
        for (int j = 0; j < 4; ++j) {
            f32x4 v = __builtin_nontemporal_load(
                (const f32x4*)(src + (size_t)kr * NDIM + nc + j * 4));
            *(f32x4*)&tile[kr][nc + j * 4] = v;
        }
    }
    __syncthreads();
    {
        const int nn = t >> 2, kc = (t & 3) * 16;
        unsigned short wbuf[16];
        #pragma unroll
        for (int j = 0; j < 16; ++j) wbuf[j] = f2bf(tile[kc + j][nn]);
        unsigned short* dst = Wt + ((size_t)e * NDIM + nb + nn) * KDIM + kb + kc;
        *(u16x8*)dst       = *(const u16x8*)&wbuf[0];
        *((u16x8*)dst + 1) = *(const u16x8*)&wbuf[8];
    }
}

// ---------------------------------------------------------------------------
// 256x256 expert GEMM, BK=32, 1024 threads = 16 waves (4x4, wave-tile 64x64,
// acc[4][4] = 64 VGPR), 4 LDS buffer pairs (128 KB), DEPTH-3 counted-vmcnt
// prefetch (vmcnt(4), never 0 in-loop), one barrier per K-tile.
// Halves cache-demand vs 128^2: (1/256+1/256)*M*N*K*2 = 537 MB/GEMM.
// LDS unit swizzle u ^= (row>>1)&3 (involution), DMA source pre-swizzled
// (rule #21): conflict-free ds_read_b128 (r6-verified 0 conflicts).
// ---------------------------------------------------------------------------
#define BAR  __builtin_amdgcn_s_barrier()

template<int LAYER>
__global__ __launch_bounds__(1024, 4) void moe_gemm(
    const unsigned short* __restrict__ Abuf,
    const unsigned short* __restrict__ Wt,
    const float* __restrict__ bias,
    const int* __restrict__ counts,
    const int* __restrict__ tiles,
    const int* __restrict__ slot_of,
    const float* __restrict__ prob_slot,
    unsigned short* __restrict__ hidden_out,
    float* __restrict__ out)
{
    const int nMt = tiles[0];
    const int bid = blockIdx.x;
    const int mt  = bid >> 3;
    const int np  = bid & 7;
    if (mt >= nMt) return;
    const int info = tiles[1 + mt];
    const int e   = info >> 16;
    const int m0  = (info & 0xffff) * 256;
    const int n0  = np * 256;
    const int n_e = counts[e];

    const int t = threadIdx.x;
    const int lane = t & 63;
    const int w = t >> 6;
    const int wm = (w >> 2) * 64;
    const int wn = (w & 3) * 64;
    const int lg = lane >> 4;          // k-unit 0..3 (8 bf16 each)

    __shared__ u16x8 As[4 * 1024];     // 4 bufs x 256 rows x 4 units (64 KB)
    __shared__ u16x8 Bs[4 * 1024];
    __shared__ int   slots_s[256];
    __shared__ float probs_s[256];

    if (t < 256) {
        int gm = m0 + t;
        int s = -1; float p = 0.f;
        if (gm < n_e) { s = slot_of[e * B_ + gm]; p = prob_slot[s]; }
        slots_s[t] = s; probs_s[t] = p;
    }
    __syncthreads();

    // staging: thread t -> row t>>2 (0..255), LDS unit t&3 (linear dest per
    // wave: 64 lanes = 1 KB). Source k-unit pre-swizzled (involution):
    const int ksw = (((t & 3) ^ ((t >> 3) & 3)) << 3);   // bf16 elems
    const unsigned short* aptr;
    const unsigned short* bptr;
    {
        const int r = t >> 2;
        int s = slots_s[r]; if (s < 0) s = 0;
        aptr = Abuf + (size_t)s * KDIM + ksw;
        bptr = Wt + ((size_t)e * NDIM + n0 + r) * KDIM + ksw;
    }

#define STG(BUF, KT) do{ \
    gload_lds16(aptr + (KT)*32, &As[(BUF)*1024 + w*64]); \
    gload_lds16(bptr + (KT)*32, &Bs[(BUF)*1024 + w*64]); }while(0)

    f32x4 acc[4][4];
    #pragma unroll
    for (int i = 0; i < 4; ++i)
        #pragma unroll
        for (int j = 0; j < 4; ++j) {
            f32x4 z = {0.f, 0.f, 0.f, 0.f};
            acc[i][j] = z;
        }

    // prologue: 3 K-tiles in flight (6 loads/thread)
    STG(0, 0); STG(1, 1); STG(2, 2);

    const int usw = (lane >> 1) & 3;   // = (frag_row>>1)&3
    for (int kt = 0; kt < 64; ++kt) {
        asm volatile("s_waitcnt vmcnt(4)" ::: "memory");   // tile kt landed
        BAR;
        int tn = kt + 3; if (tn > 63) tn = 63;             // clamped dummy tail
        STG((kt + 3) & 3, tn);

        const int base = (kt & 3) * 1024;
        bf16x8 af[4];
        #pragma unroll
        for (int mi = 0; mi < 4; ++mi) {
            const int row = wm + mi * 16 + (lane & 15);
            af[mi] = __builtin_bit_cast(bf16x8, As[base + row * 4 + (lg ^ usw)]);
        }
        #pragma unroll
        for (int ni = 0; ni < 4; ++ni) {
            const int row = wn + ni * 16 + (lane & 15);
            bf16x8 bq = __builtin_bit_cast(bf16x8, Bs[base + row * 4 + (lg ^ usw)]);
            #pragma unroll
            for (int mi = 0; mi < 4; ++mi)
                acc[mi][ni] = __builtin_amdgcn_mfma_f32_16x16x32_bf16(
                    af[mi], bq, acc[mi][ni], 0, 0, 0);
        }
    }
    asm volatile("s_waitcnt vmcnt(0)" ::: "memory");   // drain dummies

    // epilogue — C/D layout: col = lane&15, row = (lane>>4)*4 + reg
    #pragma unroll
    for (int mi = 0; mi < 4; ++mi) {
        #pragma unroll
        for (int rr = 0; rr < 4; ++rr) {
            const int rloc = wm + mi * 16 + ((lane >> 4) << 2) + rr;
            const int s = slots_s[rloc];
            if (s < 0) continue;
            #pragma unroll
            for (int ni = 0; ni < 4; ++ni) {
                const int col = n0 + wn + ni * 16 + (lane & 15);
                float v = acc[mi][ni][rr];
                if (LAYER == 1) {
                    v += bias[e * NDIM + col];
                    v = fmaxf(v, 0.f);
                    hidden_out[(size_t)s * H_ + col] = f2bf(v);
                } else {
                    v = (v + bias[e * NDIM + col]) * probs_s[rloc];
                    atomicAdd(&out[(size_t)(s >> 1) * T_ + col], v);
                }
            }
        }
    }
#undef STG
}

// ---------------------------------------------------------------------------
// ws layout: counts@0 (256B) | tiles@256 (512B) | slot_of | prob_slot |
//            A1[2B][D] bf16 | hidden[2B][H] bf16 | Wt bf16 (shared)
// ---------------------------------------------------------------------------
extern "C" void kernel_launch(void* const* d_in, const int* in_sizes, int n_in,
                              void* d_out, int out_size, void* d_ws, size_t ws_size,
                              hipStream_t stream)
{
    const float* xs = (const float*)d_in[0];
    const float* Wg = (const float*)d_in[1];
    const float* bg = (const float*)d_in[2];
    const float* W1 = (const float*)d_in[3];
    const float* b1 = (const float*)d_in[4];
    const float* W2 = (const float*)d_in[5];
    const float* b2 = (const float*)d_in[6];

    float* out      = (float*)d_out;
    float* out_topk = out + (size_t)B_ * T_;

    char* ws = (char*)d_ws;
    int*   counts    = (int*)ws;
    int*   tiles     = (int*)(ws + 256);
    int*   slot_of   = (int*)(ws + 768);
    float* prob_slot = (float*)(ws + 768 + E_ * B_ * 4);
    size_t off = 768 + (size_t)E_ * B_ * 4 + 2 * B_ * 4;
    off = (off + 255) & ~(size_t)255;
    unsigned short* A1     = (unsigned short*)(ws + off); off += (size_t)2 * B_ * D_ * 2;
    unsigned short* hidden = (unsigned short*)(ws + off); off += (size_t)2 * B_ * H_ * 2;
    unsigned short* Wtb    = (unsigned short*)(ws + off);

    hipMemsetAsync(counts, 0, 256, stream);
    hipMemsetAsync(out, 0, (size_t)B_ * T_ * sizeof(float), stream);

    dim3 tgrid(32, 32, E_), blk(256);
    dim3 ggrid(39 * 8);           // worst-case 39 m-tiles x 8 n-panels
    dim3 gblk(1024);

    moe_gating<<<dim3(B_), dim3(256), 0, stream>>>(
        xs, Wg, bg, out_topk, prob_slot, counts, slot_of, A1);
    build_tiles<<<dim3(1), dim3(64), 0, stream>>>(counts, tiles);

    wtrans<<<tgrid, blk, 0, stream>>>(W1, Wtb);
    moe_gemm<1><<<ggrid, gblk, 0, stream>>>(
        A1, Wtb, b1, counts, tiles, slot_of, prob_slot, hidden, nullptr);

    wtrans<<<tgrid, blk, 0, stream>>>(W2, Wtb);
    moe_gemm<2><<<ggrid, gblk, 0, stream>>>(
        hidden, Wtb, b2, counts, tiles, slot_of, prob_slot, nullptr, out);
}